// Round 20
// baseline (237.358 us; speedup 1.0000x reference)
//
#include <hip/hip_runtime.h>

#define NN 50000
#define NE 625000
#define HD 128
#define CAP 40        // Poisson(12.5): P(deg>40) ~ 5e-11 -> zero expected drops
#define ZROW NN       // dedicated all-zero row in h tables for masked gather slots
#define WFL (12*8*64*8)   // ushorts per layer of frag-major Wt
#define WFH (6*8*64*8)    // ushorts per staging phase (48 KB)
#define SUBD 782      // dsts per sub-bin; 64 sub-bins cover 50048 >= NN
#define NSUB 64
#define BINCAP 11008  // per-(rel,sub) capacity; expected 9766, +12 sigma

typedef __attribute__((ext_vector_type(8))) short short8;
typedef __attribute__((ext_vector_type(4))) float f32x4;
typedef __attribute__((ext_vector_type(4))) unsigned uint4v;

__device__ __forceinline__ unsigned short f2bf(float f) {
    unsigned u = __builtin_bit_cast(unsigned, f);
    u += 0x7FFFu + ((u >> 16) & 1u);
    return (unsigned short)(u >> 16);
}
__device__ __forceinline__ unsigned pack2(float lo, float hi) {
    return (unsigned)f2bf(lo) | ((unsigned)f2bf(hi) << 16);
}
__device__ __forceinline__ float bflo(unsigned v) { unsigned u = v << 16; return __builtin_bit_cast(float, u); }
__device__ __forceinline__ float bfhi(unsigned v) { unsigned u = v & 0xFFFF0000u; return __builtin_bit_cast(float, u); }

__device__ __forceinline__ void extract8(uint4v u, int j0, int cnt, unsigned* out) {
    unsigned raw[8];
    raw[0] = u.x & 0xFFFFu; raw[1] = u.x >> 16;
    raw[2] = u.y & 0xFFFFu; raw[3] = u.y >> 16;
    raw[4] = u.z & 0xFFFFu; raw[5] = u.z >> 16;
    raw[6] = u.w & 0xFFFFu; raw[7] = u.w >> 16;
    #pragma unroll
    for (int j = 0; j < 8; ++j) out[j] = (j0 + j < cnt) ? raw[j] : ZROW;
}

// P1: 64-way multi-split partition + embed (fattened blocks) + Wf (frag-major).
// cursor (128 ints) zeroed by hipMemsetAsync BEFORE this dispatch.
__global__ __launch_bounds__(256) void k_p1(
    const float* __restrict__ x, const float* __restrict__ w,
    const float* __restrict__ b, unsigned* __restrict__ h0, unsigned* __restrict__ h1,
    const int* __restrict__ ei_f, const int* __restrict__ ei_s,
    int* __restrict__ cursor, unsigned* __restrict__ bin,
    const float* __restrict__ wrf0, const float* __restrict__ wtf0, const float* __restrict__ bf0,
    const float* __restrict__ wrs0, const float* __restrict__ wts0, const float* __restrict__ bs0,
    const float* __restrict__ wrf1, const float* __restrict__ wtf1, const float* __restrict__ bf1,
    const float* __restrict__ wrs1, const float* __restrict__ wts1, const float* __restrict__ bs1,
    unsigned short* __restrict__ Wf, float* __restrict__ bcat)
{
    __shared__ int hist[NSUB], base[NSUB];
    int bid = blockIdx.x, t = threadIdx.x;
    if (bid < 490) {
        int rel = bid >= 245;
        int chunk = bid - rel * 245;
        const int* ei = rel ? ei_s : ei_f;
        if (t < NSUB) hist[t] = 0;
        __syncthreads();
        int sb[10], pp[10]; unsigned pk[10];
        int e0 = chunk * 2560 + t;
        #pragma unroll
        for (int i = 0; i < 10; ++i) {
            int e = e0 + i * 256;
            if (e < NE) {
                int d = ei[NE + e];
                int s = ei[e];
                int c = d / SUBD;                // magic-mul, compiler-generated
                sb[i] = c;
                pk[i] = ((unsigned)(d - c * SUBD) << 16) | (unsigned)s;
                pp[i] = atomicAdd(&hist[c], 1);
            } else sb[i] = -1;
        }
        __syncthreads();
        if (t < NSUB) base[t] = atomicAdd(&cursor[rel * NSUB + t], hist[t]);
        __syncthreads();
        #pragma unroll
        for (int i = 0; i < 10; ++i) {
            if (sb[i] >= 0) {
                unsigned idx = (unsigned)(base[sb[i]] + pp[i]);
                if (idx < BINCAP)
                    bin[(long)(rel * NSUB + sb[i]) * BINCAP + idx] = pk[i];
            }
        }
    } else if (bid < 2053) {
        int i0 = (bid - 490) * 2048 + t;         // 8 x 256 elems per block
        #pragma unroll
        for (int it = 0; it < 8; ++it) {
            int i = i0 + it * 256;               // [0, NN*64)
            if (i >= NN * 64) break;
            int n = i >> 6, c = (i & 63) * 2;
            float x0 = x[n*3+0], x1 = x[n*3+1], x2 = x[n*3+2];
            float v0 = fmaf(x0, w[c],   fmaf(x1, w[HD+c],   fmaf(x2, w[2*HD+c],   b[c])));
            float v1 = fmaf(x0, w[c+1], fmaf(x1, w[HD+c+1], fmaf(x2, w[2*HD+c+1], b[c+1])));
            v0 = fmaxf(v0, 0.f); v1 = fmaxf(v1, 0.f);
            h0[i] = pack2(v0, v1);
        }
    } else if (bid == 2053) {
        if (t < 64)       h0[(long)ZROW*64 + t] = 0u;
        else if (t < 128) h1[(long)ZROW*64 + (t - 64)] = 0u;
    } else {
        int i0 = (bid - 2054) * 1024 + t;        // 4 x 256 elems per block
        #pragma unroll
        for (int it = 0; it < 4; ++it) {
            int i = i0 + it * 256;               // [0, 2*128*384)
            int ln = i / 384, k = i - ln * 384;  // ln = l*128 + n
            int l = ln >> 7, n = ln & 127;
            const float* wrf = l ? wrf1 : wrf0;
            const float* wrs = l ? wrs1 : wrs0;
            const float* wtf = l ? wtf1 : wtf0;
            const float* wts = l ? wts1 : wts0;
            float v;
            if (k < 128)      v = wrf[k*HD + n];
            else if (k < 256) v = wrs[(k-128)*HD + n];
            else              v = wtf[(k-256)*HD + n] + wts[(k-256)*HD + n];
            int nt = n >> 4, m16 = n & 15;
            int kc = k >> 5, rem = k & 31, quad = rem >> 3, j = rem & 7;
            int lane = quad * 16 + m16;
            Wf[(long)(((l*12 + kc)*8 + nt)*64 + lane)*8 + j] = f2bf(0.5f * v);
            if (i < 256) {
                int ll = i >> 7, cc = i & 127;
                const float* bfp = ll ? bf1 : bf0;
                const float* bsp = ll ? bs1 : bs0;
                bcat[i] = 0.5f * (bfp[cc] + bsp[cc]);
            }
        }
    }
}

// P2: exclusive sub-bin read -> LDS-assembled buckets -> coalesced writeout.
__global__ __launch_bounds__(256) void k_p2(
    const int* __restrict__ cursor, const unsigned* __restrict__ bin,
    int* __restrict__ degF, int* __restrict__ degS,
    unsigned short* __restrict__ bktF, unsigned short* __restrict__ bktS)
{
    __shared__ unsigned short lbkt[SUBD * CAP];   // 62560 B
    __shared__ int ldeg[SUBD];                    //  3128 B
    int bid = blockIdx.x, t = threadIdx.x;
    int rel = bid >> 6;
    int sub = bid & 63;
    int cnt = min(cursor[rel * NSUB + sub], BINCAP);
    const unsigned* bp = bin + (long)(rel * NSUB + sub) * BINCAP;
    const int lo = sub * SUBD;
    const int nd = min(SUBD, NN - lo);
    for (int j = t; j < nd; j += 256) ldeg[j] = 0;
    __syncthreads();
    for (int e0 = 0; e0 < cnt; e0 += 1024) {      // 4 loads in flight
        unsigned en[4];
        #pragma unroll
        for (int q = 0; q < 4; ++q) {
            int e = e0 + q * 256 + t;
            en[q] = (e < cnt) ? bp[e] : 0xFFFFFFFFu;   // sentinel filtered below
        }
        #pragma unroll
        for (int q = 0; q < 4; ++q) {
            unsigned u = en[q] >> 16;
            if (u < (unsigned)nd) {
                int p = atomicAdd(&ldeg[u], 1);
                if (p < CAP) lbkt[u * CAP + p] = (unsigned short)(en[q] & 0xFFFFu);
            }
        }
    }
    __syncthreads();
    int* deg = rel ? degS : degF;
    unsigned short* bkt = rel ? bktS : bktF;
    for (int j = t; j < nd; j += 256) deg[lo + j] = ldeg[j];
    unsigned* gb = (unsigned*)(bkt + (long)lo * CAP);
    const unsigned* lb = (const unsigned*)lbkt;   // junk slots >= ldeg masked downstream
    const int ndw = nd * (CAP / 2);
    for (int j = t; j < ndw; j += 256) gb[j] = lb[j];
}

// agg[n] = mean over bucket[n] of h[src]. TWO nodes x TWO relations per wave:
// 8 broadcast index loads, then 64 value loads issued back-to-back before any
// accumulation — doubles in-flight loads per wave for this latency-bound gather
// (probe: if flat vs r19's 32-in-flight version, spmm is L3-throughput-bound).
__global__ __launch_bounds__(256) void k_spmm(
    const unsigned* __restrict__ h,
    const int* __restrict__ degF, const int* __restrict__ degS,
    const unsigned short* __restrict__ bktF, const unsigned short* __restrict__ bktS,
    unsigned* __restrict__ aggF, unsigned* __restrict__ aggS)
{
    int w = threadIdx.x >> 6, lane = threadIdx.x & 63;
    int n0 = blockIdx.x * 8 + w * 2;             // grid NN/8 = 6250
    int n1 = n0 + 1;
    int dF0 = degF[n0], dF1 = degF[n1];
    int dS0 = degS[n0], dS1 = degS[n1];
    int cF0 = min(dF0, CAP), cF1 = min(dF1, CAP);
    int cS0 = min(dS0, CAP), cS1 = min(dS1, CAP);
    const unsigned short* rF0 = bktF + (long)n0*CAP;
    const unsigned short* rF1 = rF0 + CAP;
    const unsigned short* rS0 = bktS + (long)n0*CAP;
    const unsigned short* rS1 = rS0 + CAP;
    uint4v uF0a = *(const uint4v*)(rF0), uF0b = *(const uint4v*)(rF0 + 8);
    uint4v uF1a = *(const uint4v*)(rF1), uF1b = *(const uint4v*)(rF1 + 8);
    uint4v uS0a = *(const uint4v*)(rS0), uS0b = *(const uint4v*)(rS0 + 8);
    uint4v uS1a = *(const uint4v*)(rS1), uS1b = *(const uint4v*)(rS1 + 8);
    unsigned iF0[16], iF1[16], iS0[16], iS1[16];
    extract8(uF0a, 0, cF0, iF0); extract8(uF0b, 8, cF0, iF0 + 8);
    extract8(uF1a, 0, cF1, iF1); extract8(uF1b, 8, cF1, iF1 + 8);
    extract8(uS0a, 0, cS0, iS0); extract8(uS0b, 8, cS0, iS0 + 8);
    extract8(uS1a, 0, cS1, iS1); extract8(uS1b, 8, cS1, iS1 + 8);
    unsigned vF0[16], vF1[16], vS0[16], vS1[16];
    #pragma unroll
    for (int j = 0; j < 16; ++j) vF0[j] = h[iF0[j]*64u + lane];
    #pragma unroll
    for (int j = 0; j < 16; ++j) vF1[j] = h[iF1[j]*64u + lane];
    #pragma unroll
    for (int j = 0; j < 16; ++j) vS0[j] = h[iS0[j]*64u + lane];
    #pragma unroll
    for (int j = 0; j < 16; ++j) vS1[j] = h[iS1[j]*64u + lane];
    float aF00 = 0.f, aF01 = 0.f, aF10 = 0.f, aF11 = 0.f;
    float aS00 = 0.f, aS01 = 0.f, aS10 = 0.f, aS11 = 0.f;
    #pragma unroll
    for (int j = 0; j < 16; ++j) { aF00 += bflo(vF0[j]); aF01 += bfhi(vF0[j]); }
    #pragma unroll
    for (int j = 0; j < 16; ++j) { aF10 += bflo(vF1[j]); aF11 += bfhi(vF1[j]); }
    #pragma unroll
    for (int j = 0; j < 16; ++j) { aS00 += bflo(vS0[j]); aS01 += bfhi(vS0[j]); }
    #pragma unroll
    for (int j = 0; j < 16; ++j) { aS10 += bflo(vS1[j]); aS11 += bfhi(vS1[j]); }
    // tails (P(deg>16) ~ 0.13 per row)
    for (int j = 16; j < cF0; j += 8) {
        uint4v u = *(const uint4v*)(rF0 + j);
        unsigned ii[8]; extract8(u, j, cF0, ii);
        unsigned vv[8];
        #pragma unroll
        for (int q = 0; q < 8; ++q) vv[q] = h[ii[q]*64u + lane];
        #pragma unroll
        for (int q = 0; q < 8; ++q) { aF00 += bflo(vv[q]); aF01 += bfhi(vv[q]); }
    }
    for (int j = 16; j < cF1; j += 8) {
        uint4v u = *(const uint4v*)(rF1 + j);
        unsigned ii[8]; extract8(u, j, cF1, ii);
        unsigned vv[8];
        #pragma unroll
        for (int q = 0; q < 8; ++q) vv[q] = h[ii[q]*64u + lane];
        #pragma unroll
        for (int q = 0; q < 8; ++q) { aF10 += bflo(vv[q]); aF11 += bfhi(vv[q]); }
    }
    for (int j = 16; j < cS0; j += 8) {
        uint4v u = *(const uint4v*)(rS0 + j);
        unsigned ii[8]; extract8(u, j, cS0, ii);
        unsigned vv[8];
        #pragma unroll
        for (int q = 0; q < 8; ++q) vv[q] = h[ii[q]*64u + lane];
        #pragma unroll
        for (int q = 0; q < 8; ++q) { aS00 += bflo(vv[q]); aS01 += bfhi(vv[q]); }
    }
    for (int j = 16; j < cS1; j += 8) {
        uint4v u = *(const uint4v*)(rS1 + j);
        unsigned ii[8]; extract8(u, j, cS1, ii);
        unsigned vv[8];
        #pragma unroll
        for (int q = 0; q < 8; ++q) vv[q] = h[ii[q]*64u + lane];
        #pragma unroll
        for (int q = 0; q < 8; ++q) { aS10 += bflo(vv[q]); aS11 += bfhi(vv[q]); }
    }
    float iF0v = 1.f / fmaxf((float)dF0, 1.f);
    float iF1v = 1.f / fmaxf((float)dF1, 1.f);
    float iS0v = 1.f / fmaxf((float)dS0, 1.f);
    float iS1v = 1.f / fmaxf((float)dS1, 1.f);
    aggF[n0*64 + lane] = pack2(aF00*iF0v, aF01*iF0v);
    aggF[n1*64 + lane] = pack2(aF10*iF1v, aF11*iF1v);
    aggS[n0*64 + lane] = pack2(aS00*iS0v, aS01*iS0v);
    aggS[n1*64 + lane] = pack2(aS10*iS1v, aS11*iS1v);
}

// out[M,128] = [A0|A1|A2](M,384, bf16) @ W + bias, W in frag-major Wf.
// Frag-major layout + LDS amortization; 64-row blocks, grid 782, 3 barriers,
// identity-layout coalesced staging, conflict-free ds_read_b128 B-frags.
// mode 0: relu -> bf16 h1. mode 1: fused classifier epilogue -> out6.
__global__ __launch_bounds__(256) void k_gemm(
    const unsigned short* __restrict__ A0, const unsigned short* __restrict__ A1,
    const unsigned short* __restrict__ A2,
    const unsigned short* __restrict__ Wf, const float* __restrict__ bias,
    unsigned short* __restrict__ outH, int mode,
    const float* __restrict__ ow, const float* __restrict__ ob,
    float* __restrict__ out6)
{
    __shared__ unsigned short Bs[WFH];           // 48 KB
    const int t = threadIdx.x;
    const int wv = t >> 6, lane = t & 63;
    const int m16 = lane & 15, quad = lane >> 4;
    const int row0 = blockIdx.x * 64 + wv * 16;
    const int r = row0 + m16;
    const bool valid = r < NN;
    f32x4 acc[8];
    #pragma unroll
    for (int nt = 0; nt < 8; ++nt) acc[nt] = (f32x4){0.f,0.f,0.f,0.f};

    #pragma unroll
    for (int ph = 0; ph < 2; ++ph) {
        if (ph) __syncthreads();                 // protect phase-0 LDS reads
        const uint4v* srcW = (const uint4v*)(Wf + (long)ph * WFH);
        uint4v* dstW = (uint4v*)Bs;
        #pragma unroll
        for (int i = 0; i < 12; ++i)             // 3072 uint4s, identity layout
            dstW[i*256 + t] = srcW[i*256 + t];
        __syncthreads();
        #pragma unroll
        for (int kl = 0; kl < 6; ++kl) {
            int kc = ph*6 + kl;
            const unsigned short* src; int kofs;
            if (kc < 4)      { src = A0; kofs = kc*32; }
            else if (kc < 8) { src = A1; kofs = kc*32 - 128; }
            else             { src = A2; kofs = kc*32 - 256; }
            short8 a;
            if (valid) a = *(const short8*)(src + (long)r*HD + kofs + quad*8);
            else       a = short8{0,0,0,0,0,0,0,0};
            #pragma unroll
            for (int nt = 0; nt < 8; ++nt) {
                short8 bfr = *(const short8*)(Bs + ((kl*8 + nt)*64 + lane)*8);
                acc[nt] = __builtin_amdgcn_mfma_f32_16x16x32_bf16(a, bfr, acc[nt], 0, 0, 0);
            }
        }
    }

    float bs[8];
    #pragma unroll
    for (int nt = 0; nt < 8; ++nt) bs[nt] = bias[nt*16 + m16];

    if (mode == 0) {
        #pragma unroll
        for (int reg = 0; reg < 4; ++reg) {
            int rr = row0 + quad*4 + reg;
            if (rr >= NN) continue;
            #pragma unroll
            for (int nt = 0; nt < 8; ++nt) {
                float v = fmaxf(acc[nt][reg] + bs[nt], 0.f);
                outH[(long)rr*HD + nt*16 + m16] = f2bf(v);
            }
        }
    } else {
        float owr[8][6];
        #pragma unroll
        for (int nt = 0; nt < 8; ++nt) {
            int c = nt*16 + m16;
            #pragma unroll
            for (int j = 0; j < 6; ++j) owr[nt][j] = ow[c*6 + j];
        }
        #pragma unroll
        for (int reg = 0; reg < 4; ++reg) {
            int rr = row0 + quad*4 + reg;
            float tj[6] = {0,0,0,0,0,0};
            #pragma unroll
            for (int nt = 0; nt < 8; ++nt) {
                float hv = acc[nt][reg] + bs[nt];
                #pragma unroll
                for (int j = 0; j < 6; ++j) tj[j] = fmaf(hv, owr[nt][j], tj[j]);
            }
            #pragma unroll
            for (int mask = 1; mask < 16; mask <<= 1)
                #pragma unroll
                for (int j = 0; j < 6; ++j) tj[j] += __shfl_xor(tj[j], mask, 64);
            if (m16 == 0 && rr < NN) {
                #pragma unroll
                for (int j = 0; j < 6; ++j) out6[(long)rr*6 + j] = tj[j] + ob[j];
            }
        }
    }
}

extern "C" void kernel_launch(void* const* d_in, const int* in_sizes, int n_in,
                              void* d_out, int out_size, void* d_ws, size_t ws_size,
                              hipStream_t stream)
{
    const float* x     = (const float*)d_in[0];
    const int*   ei_f  = (const int*)d_in[1];
    const int*   ei_s  = (const int*)d_in[2];
    const float* emb_w = (const float*)d_in[3];
    const float* emb_b = (const float*)d_in[4];
    const float* wr0f  = (const float*)d_in[5];
    const float* wt0f  = (const float*)d_in[6];
    const float* b0f   = (const float*)d_in[7];
    const float* wr0s  = (const float*)d_in[8];
    const float* wt0s  = (const float*)d_in[9];
    const float* b0s   = (const float*)d_in[10];
    const float* wr1f  = (const float*)d_in[11];
    const float* wt1f  = (const float*)d_in[12];
    const float* b1f   = (const float*)d_in[13];
    const float* wr1s  = (const float*)d_in[14];
    const float* wt1s  = (const float*)d_in[15];
    const float* b1s   = (const float*)d_in[16];
    const float* out_w = (const float*)d_in[17];
    const float* out_b = (const float*)d_in[18];
    float* out = (float*)d_out;

    char* ws = (char*)d_ws;
    size_t off = 0;
    auto alloc = [&](size_t bytes) { char* p = ws + off; off += (bytes + 255) & ~255ULL; return p; };
    unsigned* h0   = (unsigned*)alloc((size_t)(NN+1)*64*4);   // bf16x2 packed, +1 zero row
    unsigned* h1   = (unsigned*)alloc((size_t)(NN+1)*64*4);
    unsigned* aggF = (unsigned*)alloc((size_t)NN*64*4);
    unsigned* aggS = (unsigned*)alloc((size_t)NN*64*4);
    int*   degF = (int*)alloc((size_t)NN*4);
    int*   degS = (int*)alloc((size_t)NN*4);
    int*   cursor = (int*)alloc((size_t)2*NSUB*4);
    unsigned short* bktF = (unsigned short*)alloc((size_t)NN*CAP*2);
    unsigned short* bktS = (unsigned short*)alloc((size_t)NN*CAP*2);
    unsigned short* Wf = (unsigned short*)alloc((size_t)2*WFL*2);
    float* bcat = (float*)alloc((size_t)2*HD*4);
    unsigned* bin = (unsigned*)alloc((size_t)2*NSUB*BINCAP*4);

    hipMemsetAsync(cursor, 0, 2*NSUB*4, stream); // only cursor; deg fully written by k_p2

    k_p1<<<2150, 256, 0, stream>>>(x, emb_w, emb_b, h0, h1,
                                   ei_f, ei_s, cursor, bin,
                                   wr0f, wt0f, b0f, wr0s, wt0s, b0s,
                                   wr1f, wt1f, b1f, wr1s, wt1s, b1s,
                                   Wf, bcat);
    k_p2<<<128, 256, 0, stream>>>(cursor, bin, degF, degS, bktF, bktS);
    k_spmm<<<NN/8, 256, 0, stream>>>(h0, degF, degS, bktF, bktS, aggF, aggS);
    k_gemm<<<(NN + 63)/64, 256, 0, stream>>>((const unsigned short*)aggF, (const unsigned short*)aggS,
                                             (const unsigned short*)h0, Wf, bcat,
                                             (unsigned short*)h1, 0, out_w, out_b, out);
    k_spmm<<<NN/8, 256, 0, stream>>>(h1, degF, degS, bktF, bktS, aggF, aggS);
    k_gemm<<<(NN + 63)/64, 256, 0, stream>>>((const unsigned short*)aggF, (const unsigned short*)aggS,
                                             (const unsigned short*)h1, Wf + WFL, bcat + HD,
                                             (unsigned short*)h1, 1, out_w, out_b, out);
}

// Round 21
// 233.291 us; speedup vs baseline: 1.0174x; 1.0174x over previous
//
#include <hip/hip_runtime.h>

#define NN 50000
#define NE 625000
#define HD 128
#define CAP 40        // Poisson(12.5): P(deg>40) ~ 5e-11 -> zero expected drops
#define ZROW NN       // dedicated all-zero row in h tables for masked gather slots
#define WFL (12*8*64*8)   // ushorts per layer of frag-major Wt
#define WFH (6*8*64*8)    // ushorts per staging phase (48 KB)
#define SUBD 782      // dsts per sub-bin; 64 sub-bins cover 50048 >= NN
#define NSUB 64
#define BINCAP 11008  // per-(rel,sub) capacity; expected 9766, +12 sigma

typedef __attribute__((ext_vector_type(8))) short short8;
typedef __attribute__((ext_vector_type(4))) float f32x4;
typedef __attribute__((ext_vector_type(4))) unsigned uint4v;

__device__ __forceinline__ unsigned short f2bf(float f) {
    unsigned u = __builtin_bit_cast(unsigned, f);
    u += 0x7FFFu + ((u >> 16) & 1u);
    return (unsigned short)(u >> 16);
}
__device__ __forceinline__ unsigned pack2(float lo, float hi) {
    return (unsigned)f2bf(lo) | ((unsigned)f2bf(hi) << 16);
}
__device__ __forceinline__ float bflo(unsigned v) { unsigned u = v << 16; return __builtin_bit_cast(float, u); }
__device__ __forceinline__ float bfhi(unsigned v) { unsigned u = v & 0xFFFF0000u; return __builtin_bit_cast(float, u); }

__device__ __forceinline__ void extract8(uint4v u, int j0, int cnt, unsigned* out) {
    unsigned raw[8];
    raw[0] = u.x & 0xFFFFu; raw[1] = u.x >> 16;
    raw[2] = u.y & 0xFFFFu; raw[3] = u.y >> 16;
    raw[4] = u.z & 0xFFFFu; raw[5] = u.z >> 16;
    raw[6] = u.w & 0xFFFFu; raw[7] = u.w >> 16;
    #pragma unroll
    for (int j = 0; j < 8; ++j) out[j] = (j0 + j < cnt) ? raw[j] : ZROW;
}

// P1: 64-way multi-split partition + embed (fattened blocks) + Wf (frag-major).
// cursor (128 ints) zeroed by hipMemsetAsync BEFORE this dispatch.
__global__ __launch_bounds__(256) void k_p1(
    const float* __restrict__ x, const float* __restrict__ w,
    const float* __restrict__ b, unsigned* __restrict__ h0, unsigned* __restrict__ h1,
    const int* __restrict__ ei_f, const int* __restrict__ ei_s,
    int* __restrict__ cursor, unsigned* __restrict__ bin,
    const float* __restrict__ wrf0, const float* __restrict__ wtf0, const float* __restrict__ bf0,
    const float* __restrict__ wrs0, const float* __restrict__ wts0, const float* __restrict__ bs0,
    const float* __restrict__ wrf1, const float* __restrict__ wtf1, const float* __restrict__ bf1,
    const float* __restrict__ wrs1, const float* __restrict__ wts1, const float* __restrict__ bs1,
    unsigned short* __restrict__ Wf, float* __restrict__ bcat)
{
    __shared__ int hist[NSUB], base[NSUB];
    int bid = blockIdx.x, t = threadIdx.x;
    if (bid < 490) {
        int rel = bid >= 245;
        int chunk = bid - rel * 245;
        const int* ei = rel ? ei_s : ei_f;
        if (t < NSUB) hist[t] = 0;
        __syncthreads();
        int sb[10], pp[10]; unsigned pk[10];
        int e0 = chunk * 2560 + t;
        #pragma unroll
        for (int i = 0; i < 10; ++i) {
            int e = e0 + i * 256;
            if (e < NE) {
                int d = ei[NE + e];
                int s = ei[e];
                int c = d / SUBD;                // magic-mul, compiler-generated
                sb[i] = c;
                pk[i] = ((unsigned)(d - c * SUBD) << 16) | (unsigned)s;
                pp[i] = atomicAdd(&hist[c], 1);
            } else sb[i] = -1;
        }
        __syncthreads();
        if (t < NSUB) base[t] = atomicAdd(&cursor[rel * NSUB + t], hist[t]);
        __syncthreads();
        #pragma unroll
        for (int i = 0; i < 10; ++i) {
            if (sb[i] >= 0) {
                unsigned idx = (unsigned)(base[sb[i]] + pp[i]);
                if (idx < BINCAP)
                    bin[(long)(rel * NSUB + sb[i]) * BINCAP + idx] = pk[i];
            }
        }
    } else if (bid < 2053) {
        int i0 = (bid - 490) * 2048 + t;         // 8 x 256 elems per block
        #pragma unroll
        for (int it = 0; it < 8; ++it) {
            int i = i0 + it * 256;               // [0, NN*64)
            if (i >= NN * 64) break;
            int n = i >> 6, c = (i & 63) * 2;
            float x0 = x[n*3+0], x1 = x[n*3+1], x2 = x[n*3+2];
            float v0 = fmaf(x0, w[c],   fmaf(x1, w[HD+c],   fmaf(x2, w[2*HD+c],   b[c])));
            float v1 = fmaf(x0, w[c+1], fmaf(x1, w[HD+c+1], fmaf(x2, w[2*HD+c+1], b[c+1])));
            v0 = fmaxf(v0, 0.f); v1 = fmaxf(v1, 0.f);
            h0[i] = pack2(v0, v1);
        }
    } else if (bid == 2053) {
        if (t < 64)       h0[(long)ZROW*64 + t] = 0u;
        else if (t < 128) h1[(long)ZROW*64 + (t - 64)] = 0u;
    } else {
        int i0 = (bid - 2054) * 1024 + t;        // 4 x 256 elems per block
        #pragma unroll
        for (int it = 0; it < 4; ++it) {
            int i = i0 + it * 256;               // [0, 2*128*384)
            int ln = i / 384, k = i - ln * 384;  // ln = l*128 + n
            int l = ln >> 7, n = ln & 127;
            const float* wrf = l ? wrf1 : wrf0;
            const float* wrs = l ? wrs1 : wrs0;
            const float* wtf = l ? wtf1 : wtf0;
            const float* wts = l ? wts1 : wts0;
            float v;
            if (k < 128)      v = wrf[k*HD + n];
            else if (k < 256) v = wrs[(k-128)*HD + n];
            else              v = wtf[(k-256)*HD + n] + wts[(k-256)*HD + n];
            int nt = n >> 4, m16 = n & 15;
            int kc = k >> 5, rem = k & 31, quad = rem >> 3, j = rem & 7;
            int lane = quad * 16 + m16;
            Wf[(long)(((l*12 + kc)*8 + nt)*64 + lane)*8 + j] = f2bf(0.5f * v);
            if (i < 256) {
                int ll = i >> 7, cc = i & 127;
                const float* bfp = ll ? bf1 : bf0;
                const float* bsp = ll ? bs1 : bs0;
                bcat[i] = 0.5f * (bfp[cc] + bsp[cc]);
            }
        }
    }
}

// P2: exclusive sub-bin read -> LDS-assembled buckets -> coalesced writeout.
__global__ __launch_bounds__(256) void k_p2(
    const int* __restrict__ cursor, const unsigned* __restrict__ bin,
    int* __restrict__ degF, int* __restrict__ degS,
    unsigned short* __restrict__ bktF, unsigned short* __restrict__ bktS)
{
    __shared__ unsigned short lbkt[SUBD * CAP];   // 62560 B
    __shared__ int ldeg[SUBD];                    //  3128 B
    int bid = blockIdx.x, t = threadIdx.x;
    int rel = bid >> 6;
    int sub = bid & 63;
    int cnt = min(cursor[rel * NSUB + sub], BINCAP);
    const unsigned* bp = bin + (long)(rel * NSUB + sub) * BINCAP;
    const int lo = sub * SUBD;
    const int nd = min(SUBD, NN - lo);
    for (int j = t; j < nd; j += 256) ldeg[j] = 0;
    __syncthreads();
    for (int e0 = 0; e0 < cnt; e0 += 1024) {      // 4 loads in flight
        unsigned en[4];
        #pragma unroll
        for (int q = 0; q < 4; ++q) {
            int e = e0 + q * 256 + t;
            en[q] = (e < cnt) ? bp[e] : 0xFFFFFFFFu;   // sentinel filtered below
        }
        #pragma unroll
        for (int q = 0; q < 4; ++q) {
            unsigned u = en[q] >> 16;
            if (u < (unsigned)nd) {
                int p = atomicAdd(&ldeg[u], 1);
                if (p < CAP) lbkt[u * CAP + p] = (unsigned short)(en[q] & 0xFFFFu);
            }
        }
    }
    __syncthreads();
    int* deg = rel ? degS : degF;
    unsigned short* bkt = rel ? bktS : bktF;
    for (int j = t; j < nd; j += 256) deg[lo + j] = ldeg[j];
    unsigned* gb = (unsigned*)(bkt + (long)lo * CAP);
    const unsigned* lb = (const unsigned*)lbkt;   // junk slots >= ldeg masked downstream
    const int ndw = nd * (CAP / 2);
    for (int j = t; j < ndw; j += 256) gb[j] = lb[j];
}

// agg[n] = mean over bucket[n] of h[src], BOTH relations per wave (node n):
// 32 coalesced row-gathers in flight up front. Invalid slots -> zero row.
// (r20 probe: doubling in-flight loads was flat -> this kernel is at the
// cache-hierarchy throughput floor, ~320 MB/layer of irreducible gather.)
__global__ __launch_bounds__(256) void k_spmm(
    const unsigned* __restrict__ h,
    const int* __restrict__ degF, const int* __restrict__ degS,
    const unsigned short* __restrict__ bktF, const unsigned short* __restrict__ bktS,
    unsigned* __restrict__ aggF, unsigned* __restrict__ aggS)
{
    int w = threadIdx.x >> 6, lane = threadIdx.x & 63;
    int n = blockIdx.x * 4 + w;
    int dF = degF[n], dS = degS[n];
    int cF = min(dF, CAP), cS = min(dS, CAP);
    const unsigned short* rowF = bktF + (long)n*CAP;
    const unsigned short* rowS = bktS + (long)n*CAP;
    uint4v uF0 = *(const uint4v*)(rowF);
    uint4v uF1 = *(const uint4v*)(rowF + 8);
    uint4v uS0 = *(const uint4v*)(rowS);
    uint4v uS1 = *(const uint4v*)(rowS + 8);
    unsigned iF[16], iS[16];
    extract8(uF0, 0, cF, iF); extract8(uF1, 8, cF, iF + 8);
    extract8(uS0, 0, cS, iS); extract8(uS1, 8, cS, iS + 8);
    unsigned vF[16], vS[16];
    #pragma unroll
    for (int j = 0; j < 16; ++j) vF[j] = h[iF[j]*64u + lane];
    #pragma unroll
    for (int j = 0; j < 16; ++j) vS[j] = h[iS[j]*64u + lane];
    float aF0 = 0.f, aF1 = 0.f, aS0 = 0.f, aS1 = 0.f;
    #pragma unroll
    for (int j = 0; j < 16; ++j) { aF0 += bflo(vF[j]); aF1 += bfhi(vF[j]); }
    #pragma unroll
    for (int j = 0; j < 16; ++j) { aS0 += bflo(vS[j]); aS1 += bfhi(vS[j]); }
    // tails (P(deg>16) ~ 0.13)
    for (int j = 16; j < cF; j += 8) {
        uint4v u = *(const uint4v*)(rowF + j);
        unsigned ii[8];
        extract8(u, j, cF, ii);
        unsigned vv[8];
        #pragma unroll
        for (int q = 0; q < 8; ++q) vv[q] = h[ii[q]*64u + lane];
        #pragma unroll
        for (int q = 0; q < 8; ++q) { aF0 += bflo(vv[q]); aF1 += bfhi(vv[q]); }
    }
    for (int j = 16; j < cS; j += 8) {
        uint4v u = *(const uint4v*)(rowS + j);
        unsigned ii[8];
        extract8(u, j, cS, ii);
        unsigned vv[8];
        #pragma unroll
        for (int q = 0; q < 8; ++q) vv[q] = h[ii[q]*64u + lane];
        #pragma unroll
        for (int q = 0; q < 8; ++q) { aS0 += bflo(vv[q]); aS1 += bfhi(vv[q]); }
    }
    float invF = 1.f / fmaxf((float)dF, 1.f);
    float invS = 1.f / fmaxf((float)dS, 1.f);
    aggF[n*64 + lane] = pack2(aF0*invF, aF1*invF);
    aggS[n*64 + lane] = pack2(aS0*invS, aS1*invS);
}

// out[M,128] = [A0|A1|A2](M,384, bf16) @ W + bias, W in frag-major Wf.
// Frag-major layout + LDS amortization; 64-row blocks, grid 782, 3 barriers,
// identity-layout coalesced staging, conflict-free ds_read_b128 B-frags.
// mode 0: relu -> bf16 h1. mode 1: fused classifier epilogue -> out6.
__global__ __launch_bounds__(256) void k_gemm(
    const unsigned short* __restrict__ A0, const unsigned short* __restrict__ A1,
    const unsigned short* __restrict__ A2,
    const unsigned short* __restrict__ Wf, const float* __restrict__ bias,
    unsigned short* __restrict__ outH, int mode,
    const float* __restrict__ ow, const float* __restrict__ ob,
    float* __restrict__ out6)
{
    __shared__ unsigned short Bs[WFH];           // 48 KB
    const int t = threadIdx.x;
    const int wv = t >> 6, lane = t & 63;
    const int m16 = lane & 15, quad = lane >> 4;
    const int row0 = blockIdx.x * 64 + wv * 16;
    const int r = row0 + m16;
    const bool valid = r < NN;
    f32x4 acc[8];
    #pragma unroll
    for (int nt = 0; nt < 8; ++nt) acc[nt] = (f32x4){0.f,0.f,0.f,0.f};

    #pragma unroll
    for (int ph = 0; ph < 2; ++ph) {
        if (ph) __syncthreads();                 // protect phase-0 LDS reads
        const uint4v* srcW = (const uint4v*)(Wf + (long)ph * WFH);
        uint4v* dstW = (uint4v*)Bs;
        #pragma unroll
        for (int i = 0; i < 12; ++i)             // 3072 uint4s, identity layout
            dstW[i*256 + t] = srcW[i*256 + t];
        __syncthreads();
        #pragma unroll
        for (int kl = 0; kl < 6; ++kl) {
            int kc = ph*6 + kl;
            const unsigned short* src; int kofs;
            if (kc < 4)      { src = A0; kofs = kc*32; }
            else if (kc < 8) { src = A1; kofs = kc*32 - 128; }
            else             { src = A2; kofs = kc*32 - 256; }
            short8 a;
            if (valid) a = *(const short8*)(src + (long)r*HD + kofs + quad*8);
            else       a = short8{0,0,0,0,0,0,0,0};
            #pragma unroll
            for (int nt = 0; nt < 8; ++nt) {
                short8 bfr = *(const short8*)(Bs + ((kl*8 + nt)*64 + lane)*8);
                acc[nt] = __builtin_amdgcn_mfma_f32_16x16x32_bf16(a, bfr, acc[nt], 0, 0, 0);
            }
        }
    }

    float bs[8];
    #pragma unroll
    for (int nt = 0; nt < 8; ++nt) bs[nt] = bias[nt*16 + m16];

    if (mode == 0) {
        #pragma unroll
        for (int reg = 0; reg < 4; ++reg) {
            int rr = row0 + quad*4 + reg;
            if (rr >= NN) continue;
            #pragma unroll
            for (int nt = 0; nt < 8; ++nt) {
                float v = fmaxf(acc[nt][reg] + bs[nt], 0.f);
                outH[(long)rr*HD + nt*16 + m16] = f2bf(v);
            }
        }
    } else {
        float owr[8][6];
        #pragma unroll
        for (int nt = 0; nt < 8; ++nt) {
            int c = nt*16 + m16;
            #pragma unroll
            for (int j = 0; j < 6; ++j) owr[nt][j] = ow[c*6 + j];
        }
        #pragma unroll
        for (int reg = 0; reg < 4; ++reg) {
            int rr = row0 + quad*4 + reg;
            float tj[6] = {0,0,0,0,0,0};
            #pragma unroll
            for (int nt = 0; nt < 8; ++nt) {
                float hv = acc[nt][reg] + bs[nt];
                #pragma unroll
                for (int j = 0; j < 6; ++j) tj[j] = fmaf(hv, owr[nt][j], tj[j]);
            }
            #pragma unroll
            for (int mask = 1; mask < 16; mask <<= 1)
                #pragma unroll
                for (int j = 0; j < 6; ++j) tj[j] += __shfl_xor(tj[j], mask, 64);
            if (m16 == 0 && rr < NN) {
                #pragma unroll
                for (int j = 0; j < 6; ++j) out6[(long)rr*6 + j] = tj[j] + ob[j];
            }
        }
    }
}

extern "C" void kernel_launch(void* const* d_in, const int* in_sizes, int n_in,
                              void* d_out, int out_size, void* d_ws, size_t ws_size,
                              hipStream_t stream)
{
    const float* x     = (const float*)d_in[0];
    const int*   ei_f  = (const int*)d_in[1];
    const int*   ei_s  = (const int*)d_in[2];
    const float* emb_w = (const float*)d_in[3];
    const float* emb_b = (const float*)d_in[4];
    const float* wr0f  = (const float*)d_in[5];
    const float* wt0f  = (const float*)d_in[6];
    const float* b0f   = (const float*)d_in[7];
    const float* wr0s  = (const float*)d_in[8];
    const float* wt0s  = (const float*)d_in[9];
    const float* b0s   = (const float*)d_in[10];
    const float* wr1f  = (const float*)d_in[11];
    const float* wt1f  = (const float*)d_in[12];
    const float* b1f   = (const float*)d_in[13];
    const float* wr1s  = (const float*)d_in[14];
    const float* wt1s  = (const float*)d_in[15];
    const float* b1s   = (const float*)d_in[16];
    const float* out_w = (const float*)d_in[17];
    const float* out_b = (const float*)d_in[18];
    float* out = (float*)d_out;

    char* ws = (char*)d_ws;
    size_t off = 0;
    auto alloc = [&](size_t bytes) { char* p = ws + off; off += (bytes + 255) & ~255ULL; return p; };
    unsigned* h0   = (unsigned*)alloc((size_t)(NN+1)*64*4);   // bf16x2 packed, +1 zero row
    unsigned* h1   = (unsigned*)alloc((size_t)(NN+1)*64*4);
    unsigned* aggF = (unsigned*)alloc((size_t)NN*64*4);
    unsigned* aggS = (unsigned*)alloc((size_t)NN*64*4);
    int*   degF = (int*)alloc((size_t)NN*4);
    int*   degS = (int*)alloc((size_t)NN*4);
    int*   cursor = (int*)alloc((size_t)2*NSUB*4);
    unsigned short* bktF = (unsigned short*)alloc((size_t)NN*CAP*2);
    unsigned short* bktS = (unsigned short*)alloc((size_t)NN*CAP*2);
    unsigned short* Wf = (unsigned short*)alloc((size_t)2*WFL*2);
    float* bcat = (float*)alloc((size_t)2*HD*4);
    unsigned* bin = (unsigned*)alloc((size_t)2*NSUB*BINCAP*4);

    hipMemsetAsync(cursor, 0, 2*NSUB*4, stream); // only cursor; deg fully written by k_p2

    k_p1<<<2150, 256, 0, stream>>>(x, emb_w, emb_b, h0, h1,
                                   ei_f, ei_s, cursor, bin,
                                   wr0f, wt0f, b0f, wr0s, wt0s, b0s,
                                   wr1f, wt1f, b1f, wr1s, wt1s, b1s,
                                   Wf, bcat);
    k_p2<<<128, 256, 0, stream>>>(cursor, bin, degF, degS, bktF, bktS);
    k_spmm<<<NN/4, 256, 0, stream>>>(h0, degF, degS, bktF, bktS, aggF, aggS);
    k_gemm<<<(NN + 63)/64, 256, 0, stream>>>((const unsigned short*)aggF, (const unsigned short*)aggS,
                                             (const unsigned short*)h0, Wf, bcat,
                                             (unsigned short*)h1, 0, out_w, out_b, out);
    k_spmm<<<NN/4, 256, 0, stream>>>(h1, degF, degS, bktF, bktS, aggF, aggS);
    k_gemm<<<(NN + 63)/64, 256, 0, stream>>>((const unsigned short*)aggF, (const unsigned short*)aggS,
                                             (const unsigned short*)h1, Wf + WFL, bcat + HD,
                                             (unsigned short*)h1, 1, out_w, out_b, out);
}